// Round 1
// baseline (661.447 us; speedup 1.0000x reference)
//
#include <hip/hip_runtime.h>
#include <math.h>

#define DIN 17
#define DH  128
#define NH  4
#define CC  32
#define NL  3
#define NEG 0.2f

// ---------------- tiny per-layer edge-projection scalars ----------------
// p[l,h] = sum_{d,c} enc_edge_w[d] * We[l,d,h*32+c] * a_edge[l,h,c]
// q[l,h] = same with enc_edge_b
__global__ void pq_kernel(const float* __restrict__ ew, const float* __restrict__ eb,
                          const float* __restrict__ We, const float* __restrict__ ae,
                          float* __restrict__ pq) {
    int lh = blockIdx.x;            // 0..11
    int l = lh >> 2, h = lh & 3;
    int t = threadIdx.x;            // 64
    const float* Wel = We + l * DH * DH;
    const float* ael = ae + l * DH + h * CC;
    float p = 0.f, q = 0.f;
    for (int d = t; d < DH; d += 64) {
        const float* row = Wel + d * DH + h * CC;
        float wp = 0.f;
        for (int c = 0; c < CC; ++c) wp += row[c] * ael[c];
        p += ew[d] * wp;
        q += eb[d] * wp;
    }
    for (int o = 32; o > 0; o >>= 1) { p += __shfl_down(p, o, 64); q += __shfl_down(q, o, 64); }
    if (t == 0) { pq[lh * 2 + 0] = p; pq[lh * 2 + 1] = q; }
}

// ---------------- node encoder: h = x @ Wn + bn ----------------
__global__ void enc_kernel(const float* __restrict__ x, const float* __restrict__ W,
                           const float* __restrict__ b, float* __restrict__ h, int N) {
    int r0 = blockIdx.x * 4;
    int t = threadIdx.x;  // 128
    __shared__ float xs[4][DIN];
    for (int i = t; i < 4 * DIN; i += 128) {
        int r = i / DIN, k = i % DIN;
        if (r0 + r < N) xs[r][k] = x[(size_t)(r0 + r) * DIN + k];
    }
    __syncthreads();
    float bias = b[t];
    for (int i = 0; i < 4; ++i) {
        int r = r0 + i;
        if (r >= N) break;
        float acc = bias;
        for (int k = 0; k < DIN; ++k) acc += xs[i][k] * W[k * DH + t];
        h[(size_t)r * DH + t] = acc;
    }
}

// ---------------- per-layer node transform: h1 = h@W, alpha_src/dst ----------------
__global__ void layer_node(const float* __restrict__ h, const float* __restrict__ W,
                           const float* __restrict__ asv, const float* __restrict__ adv,
                           float* __restrict__ h1, float* __restrict__ as_, float* __restrict__ ad_,
                           int N) {
    int r0 = blockIdx.x * 4;
    int t = threadIdx.x;  // 128
    __shared__ float rows[4][DH];
    for (int i = 0; i < 4; ++i) {
        int r = r0 + i;
        rows[i][t] = (r < N) ? h[(size_t)r * DH + t] : 0.f;
    }
    __syncthreads();
    float acc0 = 0.f, acc1 = 0.f, acc2 = 0.f, acc3 = 0.f;
    for (int k = 0; k < DH; ++k) {
        float w = W[k * DH + t];
        acc0 += rows[0][k] * w;
        acc1 += rows[1][k] * w;
        acc2 += rows[2][k] * w;
        acc3 += rows[3][k] * w;
    }
    float a_s = asv[t], a_d = adv[t];
    float accs[4] = {acc0, acc1, acc2, acc3};
    for (int i = 0; i < 4; ++i) {
        int r = r0 + i;
        if (r >= N) break;
        h1[(size_t)r * DH + t] = accs[i];
        float ps = accs[i] * a_s, pd = accs[i] * a_d;
        for (int o = 16; o > 0; o >>= 1) { ps += __shfl_down(ps, o, 32); pd += __shfl_down(pd, o, 32); }
        if ((t & 31) == 0) {
            as_[r * NH + (t >> 5)] = ps;
            ad_[r * NH + (t >> 5)] = pd;
        }
    }
}

// ---------------- degree + edge-attr sum per dst ----------------
__global__ void deg_kernel(const int* __restrict__ ei, const float* __restrict__ ea,
                           int* __restrict__ deg, float* __restrict__ asum, int E) {
    int e = blockIdx.x * 256 + threadIdx.x;
    if (e >= E) return;
    int d = ei[E + e];
    atomicAdd(&deg[d], 1);
    atomicAdd(&asum[d], ea[e]);
}

// ---------------- 3-kernel exclusive scan over deg ----------------
__global__ void scan1(const int* __restrict__ deg, int* __restrict__ offs,
                      int* __restrict__ bsum, int N) {
    __shared__ int buf[1024];
    int b = blockIdx.x, t = threadIdx.x, i = b * 1024 + t;
    int v = (i < N) ? deg[i] : 0;
    buf[t] = v;
    __syncthreads();
    int val = v;
    for (int o = 1; o < 1024; o <<= 1) {
        int add = (t >= o) ? buf[t - o] : 0;
        __syncthreads();
        val += add;
        buf[t] = val;
        __syncthreads();
    }
    if (i < N) offs[i] = val - v;  // exclusive within block
    if (t == 1023) bsum[b] = val;
}

__global__ void scan2(const int* __restrict__ bsum, int* __restrict__ boff, int nb) {
    if (threadIdx.x == 0) {
        int s = 0;
        for (int b = 0; b < nb; ++b) { boff[b] = s; s += bsum[b]; }
    }
}

__global__ void scan3(int* __restrict__ offs, int* __restrict__ cursor,
                      const int* __restrict__ boff, int N) {
    int i = blockIdx.x * 1024 + threadIdx.x;
    if (i >= N) return;
    int v = offs[i] + boff[blockIdx.x];
    offs[i] = v;
    cursor[i] = v;
}

// ---------------- scatter edges into CSR by dst ----------------
__global__ void scatter_kernel(const int* __restrict__ ei, const float* __restrict__ ea,
                               int* __restrict__ cursor, int* __restrict__ csr_src,
                               float* __restrict__ csr_a, int E) {
    int e = blockIdx.x * 256 + threadIdx.x;
    if (e >= E) return;
    int d = ei[E + e];
    int pos = atomicAdd(&cursor[d], 1);
    csr_src[pos] = ei[e];
    csr_a[pos] = ea[e];
}

// ---------------- per-node attention + aggregation (one wave per node) ----------------
__global__ void agg_kernel(const float* __restrict__ h1, const float* __restrict__ as_,
                           const float* __restrict__ ad_, const int* __restrict__ offs,
                           const int* __restrict__ deg, const float* __restrict__ asum,
                           const int* __restrict__ csr_src, const float* __restrict__ csr_a,
                           const float* __restrict__ pql, const float* __restrict__ bias,
                           float* __restrict__ hout, int N) {
    int n = blockIdx.x;
    if (n >= N) return;
    int lane = threadIdx.x;         // 64
    int hd = lane >> 4;             // head of my 2 channels
    int c0 = lane * 2;
    int off = offs[n], dg = deg[n];
    float adn = ad_[n * NH + hd];
    float pa = pql[hd * 2 + 0], qa = pql[hd * 2 + 1];

    // self-loop logit (loop attr = mean of incoming edge attrs; exactly 0 if deg==0)
    float sa = asum[n] / fmaxf((float)dg, 1.f);
    float ael = (dg > 0) ? (sa * pa + qa) : 0.f;
    float l0 = as_[n * NH + hd] + adn + ael;
    l0 = (l0 > 0.f) ? l0 : NEG * l0;

    // pass 1: max
    float mx = l0;
    for (int i = 0; i < dg; ++i) {
        int s = csr_src[off + i];
        float a = csr_a[off + i];
        float lg = as_[s * NH + hd] + adn + a * pa + qa;
        lg = (lg > 0.f) ? lg : NEG * lg;
        mx = fmaxf(mx, lg);
    }

    // pass 2: exp-sum + weighted gather
    float den = 0.f, a0 = 0.f, a1 = 0.f;
    {
        float num = expf(l0 - mx);
        den += num;
        a0 += num * h1[(size_t)n * DH + c0];
        a1 += num * h1[(size_t)n * DH + c0 + 1];
    }
    for (int i = 0; i < dg; ++i) {
        int s = csr_src[off + i];
        float a = csr_a[off + i];
        float lg = as_[s * NH + hd] + adn + a * pa + qa;
        lg = (lg > 0.f) ? lg : NEG * lg;
        float num = expf(lg - mx);
        den += num;
        a0 += num * h1[(size_t)s * DH + c0];
        a1 += num * h1[(size_t)s * DH + c0 + 1];
    }
    float inv = 1.f / (den + 1e-16f);
    float o0 = a0 * inv + bias[c0];
    float o1 = a1 * inv + bias[c0 + 1];
    o0 = (o0 > 0.f) ? o0 : expm1f(o0);   // elu
    o1 = (o1 > 0.f) ? o1 : expm1f(o1);
    hout[(size_t)n * DH + c0] = o0;
    hout[(size_t)n * DH + c0 + 1] = o1;
}

// ---------------- decoder: relu(h@w1+b1)@w2+b2 ----------------
__global__ void dec_kernel(const float* __restrict__ h, const float* __restrict__ w1,
                           const float* __restrict__ b1, const float* __restrict__ w2,
                           const float* __restrict__ b2, float* __restrict__ out, int N) {
    int r0 = blockIdx.x * 4;
    int t = threadIdx.x;  // 128
    __shared__ float rows[4][DH];
    __shared__ float hid[4][DH];
    for (int i = 0; i < 4; ++i) {
        int r = r0 + i;
        rows[i][t] = (r < N) ? h[(size_t)r * DH + t] : 0.f;
    }
    __syncthreads();
    float bb = b1[t];
    for (int i = 0; i < 4; ++i) {
        float acc = bb;
        for (int k = 0; k < DH; ++k) acc += rows[i][k] * w1[k * DH + t];
        hid[i][t] = fmaxf(acc, 0.f);
    }
    __syncthreads();
    int i = t >> 5, c = t & 31;
    float p0 = 0.f, p1 = 0.f;
    for (int d = c; d < DH; d += 32) {
        float v = hid[i][d];
        p0 += v * w2[d * 2 + 0];
        p1 += v * w2[d * 2 + 1];
    }
    for (int o = 16; o > 0; o >>= 1) { p0 += __shfl_down(p0, o, 32); p1 += __shfl_down(p1, o, 32); }
    int r = r0 + i;
    if (c == 0 && r < N) {
        out[r * 2 + 0] = p0 + b2[0];
        out[r * 2 + 1] = p1 + b2[1];
    }
}

extern "C" void kernel_launch(void* const* d_in, const int* in_sizes, int n_in,
                              void* d_out, int out_size, void* d_ws, size_t ws_size,
                              hipStream_t stream) {
    const float* x          = (const float*)d_in[0];
    const int*   ei         = (const int*)d_in[1];
    const float* eattr      = (const float*)d_in[2];
    const float* enc_node_w = (const float*)d_in[3];
    const float* enc_node_b = (const float*)d_in[4];
    const float* enc_edge_w = (const float*)d_in[5];
    const float* enc_edge_b = (const float*)d_in[6];
    const float* lin_w      = (const float*)d_in[7];
    const float* lin_edge_w = (const float*)d_in[8];
    const float* att_src    = (const float*)d_in[9];
    const float* att_dst    = (const float*)d_in[10];
    const float* att_edge   = (const float*)d_in[11];
    const float* gat_bias   = (const float*)d_in[12];
    const float* dec_w1     = (const float*)d_in[13];
    const float* dec_b1     = (const float*)d_in[14];
    const float* dec_w2     = (const float*)d_in[15];
    const float* dec_b2     = (const float*)d_in[16];

    const int E = in_sizes[2];          // DE == 1
    const int N = in_sizes[0] / DIN;

    // workspace carve (512B aligned)
    char* w = (char*)d_ws;
    auto alloc = [&](size_t bytes) -> void* {
        void* p = (void*)w;
        w += (bytes + 511) & ~((size_t)511);
        return p;
    };
    float* h      = (float*)alloc((size_t)N * DH * 4);
    float* h1     = (float*)alloc((size_t)N * DH * 4);
    float* as_    = (float*)alloc((size_t)N * NH * 4);
    float* ad_    = (float*)alloc((size_t)N * NH * 4);
    int*   deg    = (int*)alloc((size_t)N * 4);
    float* asum   = (float*)alloc((size_t)N * 4);
    int*   offs   = (int*)alloc((size_t)N * 4);
    int*   cursor = (int*)alloc((size_t)N * 4);
    int*   bsum   = (int*)alloc(64 * 4);
    int*   boff   = (int*)alloc(64 * 4);
    int*   csrs   = (int*)alloc((size_t)E * 4);
    float* csra   = (float*)alloc((size_t)E * 4);
    float* pq     = (float*)alloc(NL * NH * 2 * 4);

    hipMemsetAsync(deg, 0, (size_t)N * 4, stream);
    hipMemsetAsync(asum, 0, (size_t)N * 4, stream);

    pq_kernel<<<NL * NH, 64, 0, stream>>>(enc_edge_w, enc_edge_b, lin_edge_w, att_edge, pq);
    enc_kernel<<<(N + 3) / 4, 128, 0, stream>>>(x, enc_node_w, enc_node_b, h, N);
    deg_kernel<<<(E + 255) / 256, 256, 0, stream>>>(ei, eattr, deg, asum, E);

    int nb = (N + 1023) / 1024;
    scan1<<<nb, 1024, 0, stream>>>(deg, offs, bsum, N);
    scan2<<<1, 64, 0, stream>>>(bsum, boff, nb);
    scan3<<<nb, 1024, 0, stream>>>(offs, cursor, boff, N);
    scatter_kernel<<<(E + 255) / 256, 256, 0, stream>>>(ei, eattr, cursor, csrs, csra, E);

    for (int l = 0; l < NL; ++l) {
        layer_node<<<(N + 3) / 4, 128, 0, stream>>>(h, lin_w + (size_t)l * DH * DH,
                                                    att_src + l * DH, att_dst + l * DH,
                                                    h1, as_, ad_, N);
        agg_kernel<<<N, 64, 0, stream>>>(h1, as_, ad_, offs, deg, asum, csrs, csra,
                                         pq + l * NH * 2, gat_bias + l * DH, h, N);
    }
    dec_kernel<<<(N + 3) / 4, 128, 0, stream>>>(h, dec_w1, dec_b1, dec_w2, dec_b2,
                                                (float*)d_out, N);
}